// Round 1
// baseline (379.794 us; speedup 1.0000x reference)
//
#include <hip/hip_runtime.h>

#define N_TOK 16384
#define N_EMB 8192
#define DIM   512
#define KSPLIT 4
#define KB    (N_EMB / KSPLIT)   // 2048 codes per block

typedef __attribute__((ext_vector_type(8))) short bf16x8;
typedef __attribute__((ext_vector_type(4))) float f32x4;
typedef __attribute__((ext_vector_type(4))) unsigned short u16x4;
typedef unsigned short u16;

__device__ __forceinline__ u16 f2bf(float f) {
    unsigned u = __float_as_uint(f);
    u += 0x7fffu + ((u >> 16) & 1u);
    return (u16)(u >> 16);
}
__device__ __forceinline__ float bf2f(u16 h) {
    return __uint_as_float(((unsigned)h) << 16);
}

__device__ __forceinline__ void gload16(const void* g, void* l) {
    __builtin_amdgcn_global_load_lds(
        (const __attribute__((address_space(1))) unsigned int*)g,
        (__attribute__((address_space(3))) unsigned int*)l, 16, 0, 0);
}

// ---------------- prep: split x into bf16 hi/lo ----------------
__global__ void prep_x_kernel(const float* __restrict__ x,
                              u16* __restrict__ xhi, u16* __restrict__ xlo) {
    int i = (blockIdx.x * 256 + threadIdx.x) * 4;
    float4 v = *(const float4*)(x + i);
    u16x4 h, l;
    h.x = f2bf(v.x); l.x = f2bf(v.x - bf2f(h.x));
    h.y = f2bf(v.y); l.y = f2bf(v.y - bf2f(h.y));
    h.z = f2bf(v.z); l.z = f2bf(v.z - bf2f(h.z));
    h.w = f2bf(v.w); l.w = f2bf(v.w - bf2f(h.w));
    *(u16x4*)(xhi + i) = h;
    *(u16x4*)(xlo + i) = l;
}

// ---------------- prep: split w + wsq (one wave per row) ----------------
__global__ void prep_w_kernel(const float* __restrict__ w,
                              u16* __restrict__ whi, u16* __restrict__ wlo,
                              float* __restrict__ wsq) {
    const int tid = threadIdx.x, lane = tid & 63, wv = tid >> 6;
    const int row = blockIdx.x * 4 + wv;
    const float* src = w + (size_t)row * DIM;
    float s = 0.f;
#pragma unroll
    for (int j = 0; j < 2; ++j) {
        int d = j * 256 + lane * 4;
        float4 v = *(const float4*)(src + d);
        u16x4 h, l;
        h.x = f2bf(v.x); l.x = f2bf(v.x - bf2f(h.x));
        h.y = f2bf(v.y); l.y = f2bf(v.y - bf2f(h.y));
        h.z = f2bf(v.z); l.z = f2bf(v.z - bf2f(h.z));
        h.w = f2bf(v.w); l.w = f2bf(v.w - bf2f(h.w));
        *(u16x4*)(whi + (size_t)row * DIM + d) = h;
        *(u16x4*)(wlo + (size_t)row * DIM + d) = l;
        s += v.x * v.x + v.y * v.y + v.z * v.z + v.w * v.w;
    }
#pragma unroll
    for (int off = 1; off < 64; off <<= 1) s += __shfl_xor(s, off);
    if (lane == 0) wsq[row] = s;
}

// ---------------- main: 3-pass split-bf16 GEMM + streaming argmin ----------------
__global__ __launch_bounds__(256, 2)
void gemm_argmin_kernel(const u16* __restrict__ xhi, const u16* __restrict__ xlo,
                        const u16* __restrict__ whi, const u16* __restrict__ wlo,
                        const float* __restrict__ wsq,
                        float* __restrict__ wsval, int* __restrict__ wsidx) {
    // 4 tiles of [128][64] bf16 = 64 KiB exactly. XOR-swizzled layout:
    // element (row,k) lives at byte  row*128 + ((2k) ^ ((row&7)<<4)).
    __shared__ u16 sm[4][128 * 64];
    const int tid = threadIdx.x;
    const int lane = tid & 63, wv = tid >> 6;
    const int wm = wv >> 1, wn = wv & 1;
    const int RB = blockIdx.x * 128;
    const int CB = blockIdx.y * KB;

    float runv[16];
    int   runi[16];
#pragma unroll
    for (int e = 0; e < 16; ++e) { runv[e] = 3.4e38f; runi[e] = 0; }

    for (int ch = 0; ch < KB / 128; ++ch) {
        const int cb = CB + ch * 128;
        float wq[4];
#pragma unroll
        for (int ni = 0; ni < 4; ++ni)
            wq[ni] = wsq[cb + wn * 64 + ni * 16 + (lane & 15)];

        f32x4 acc[4][4];
#pragma unroll
        for (int mi = 0; mi < 4; ++mi)
#pragma unroll
            for (int ni = 0; ni < 4; ++ni)
                acc[mi][ni] = (f32x4){0.f, 0.f, 0.f, 0.f};

        for (int ds = 0; ds < DIM / 64; ++ds) {
            const int d0 = ds * 64;
            __syncthreads();   // previous tile reads complete
            // stage 4 tiles; per wave 4 issues/tile; dest is linear
            // (base + lane*16); source column pre-swizzled (m173 pattern)
#pragma unroll
            for (int i = 0; i < 4; ++i) {
                int seg = i * 4 + wv;                  // wave-uniform
                int row = seg * 8 + (lane >> 3);       // tile row this lane feeds
                int lc  = (lane & 7) ^ (lane >> 3);    // pre-swizzled col chunk
                size_t soA = (size_t)(RB + row) * DIM + d0 + lc * 8;
                size_t soB = (size_t)(cb + row) * DIM + d0 + lc * 8;
                gload16(xhi + soA, &sm[0][seg * 512]);
                gload16(xlo + soA, &sm[1][seg * 512]);
                gload16(whi + soB, &sm[2][seg * 512]);
                gload16(wlo + soB, &sm[3][seg * 512]);
            }
            __syncthreads();   // staging drained (compiler emits vmcnt(0))

#pragma unroll
            for (int kk = 0; kk < 2; ++kk) {
                bf16x8 ah[4], al[4], bh[4], bl[4];
#pragma unroll
                for (int mi = 0; mi < 4; ++mi) {
                    int row = wm * 64 + mi * 16 + (lane & 15);
                    int off = row * 128 +
                              ((kk * 64 + (lane >> 4) * 16) ^ ((lane & 7) << 4));
                    ah[mi] = *(const bf16x8*)((const char*)&sm[0][0] + off);
                    al[mi] = *(const bf16x8*)((const char*)&sm[1][0] + off);
                }
#pragma unroll
                for (int ni = 0; ni < 4; ++ni) {
                    int row = wn * 64 + ni * 16 + (lane & 15);
                    int off = row * 128 +
                              ((kk * 64 + (lane >> 4) * 16) ^ ((lane & 7) << 4));
                    bh[ni] = *(const bf16x8*)((const char*)&sm[2][0] + off);
                    bl[ni] = *(const bf16x8*)((const char*)&sm[3][0] + off);
                }
#pragma unroll
                for (int mi = 0; mi < 4; ++mi)
#pragma unroll
                    for (int ni = 0; ni < 4; ++ni) {
                        acc[mi][ni] = __builtin_amdgcn_mfma_f32_16x16x32_bf16(
                            ah[mi], bh[ni], acc[mi][ni], 0, 0, 0);
                        acc[mi][ni] = __builtin_amdgcn_mfma_f32_16x16x32_bf16(
                            ah[mi], bl[ni], acc[mi][ni], 0, 0, 0);
                        acc[mi][ni] = __builtin_amdgcn_mfma_f32_16x16x32_bf16(
                            al[mi], bh[ni], acc[mi][ni], 0, 0, 0);
                    }
            }
        }
        // epilogue: score = wsq - 2*S ; streaming argmin (cols ascending,
        // strict < keeps lowest index on ties)
#pragma unroll
        for (int mi = 0; mi < 4; ++mi)
#pragma unroll
            for (int ni = 0; ni < 4; ++ni) {
                int idx = cb + wn * 64 + ni * 16 + (lane & 15);
#pragma unroll
                for (int r = 0; r < 4; ++r) {
                    float sc = wq[ni] - 2.0f * acc[mi][ni][r];
                    int e = mi * 4 + r;
                    if (sc < runv[e]) { runv[e] = sc; runi[e] = idx; }
                }
            }
    }

    // cross-lane reduce (lanes 0..15 of each group share rows, own cols)
    __syncthreads();
    float* mv  = (float*)&sm[0][0];                 // [2][128]
    int*   mi_ = (int*)((char*)&sm[0][0] + 1024);   // [2][128]
#pragma unroll
    for (int e = 0; e < 16; ++e) {
        float v = runv[e];
        int   ix = runi[e];
#pragma unroll
        for (int off = 1; off < 16; off <<= 1) {
            float ov = __shfl_xor(v, off);
            int   oi = __shfl_xor(ix, off);
            if (ov < v || (ov == v && oi < ix)) { v = ov; ix = oi; }
        }
        if ((lane & 15) == 0) {
            int rl = wm * 64 + (e >> 2) * 16 + (lane >> 4) * 4 + (e & 3);
            mv[wn * 128 + rl]  = v;
            mi_[wn * 128 + rl] = ix;
        }
    }
    __syncthreads();
    if (tid < 128) {
        float v0 = mv[tid];       int i0 = mi_[tid];
        float v1 = mv[128 + tid]; int i1 = mi_[128 + tid];
        if (v1 < v0 || (v1 == v0 && i1 < i0)) { v0 = v1; i0 = i1; }
        wsval[(size_t)(RB + tid) * KSPLIT + blockIdx.y] = v0;
        wsidx[(size_t)(RB + tid) * KSPLIT + blockIdx.y] = i0;
    }
}

// ---------------- merge ksplits + gather + loss partials ----------------
__global__ void gather_loss_kernel(const float* __restrict__ w, const float* __restrict__ x,
                                   const float* __restrict__ wsval, const int* __restrict__ wsidx,
                                   float* __restrict__ out, float* __restrict__ lossp) {
    const int tid = threadIdx.x, lane = tid & 63, wv = tid >> 6;
    const int t = blockIdx.x * 4 + wv;
    int bi = 0;
    if (lane == 0) {
        float bv = wsval[(size_t)t * KSPLIT];
        bi = wsidx[(size_t)t * KSPLIT];
#pragma unroll
        for (int ks = 1; ks < KSPLIT; ++ks) {
            float v = wsval[(size_t)t * KSPLIT + ks];
            int  ix = wsidx[(size_t)t * KSPLIT + ks];
            if (v < bv || (v == bv && ix < bi)) { bv = v; bi = ix; }
        }
    }
    bi = __shfl(bi, 0);
    const float* wr = w + (size_t)bi * DIM;
    const float* xr = x + (size_t)t * DIM;
    float* orow = out + (size_t)t * DIM;
    float s = 0.f;
#pragma unroll
    for (int j = 0; j < 2; ++j) {
        int d = j * 256 + lane * 4;
        float4 a = *(const float4*)(wr + d);
        float4 b = *(const float4*)(xr + d);
        *(float4*)(orow + d) = a;
        float d0 = a.x - b.x, d1 = a.y - b.y, d2 = a.z - b.z, d3 = a.w - b.w;
        s += d0 * d0 + d1 * d1 + d2 * d2 + d3 * d3;
    }
#pragma unroll
    for (int off = 1; off < 64; off <<= 1) s += __shfl_xor(s, off);
    __shared__ float ls[4];
    if (lane == 0) ls[wv] = s;
    __syncthreads();
    if (tid == 0) lossp[blockIdx.x] = ls[0] + ls[1] + ls[2] + ls[3];
}

// ---------------- deterministic final loss reduce ----------------
__global__ void loss_final_kernel(const float* __restrict__ lossp, float* __restrict__ out) {
    __shared__ float red[256];
    float s = 0.f;
    for (int i = threadIdx.x; i < N_TOK / 4; i += 256) s += lossp[i];
    red[threadIdx.x] = s;
    __syncthreads();
    for (int st = 128; st > 0; st >>= 1) {
        if (threadIdx.x < st) red[threadIdx.x] += red[threadIdx.x + st];
        __syncthreads();
    }
    // vq_loss = (1 + BETA) * mean((q - x)^2)
    if (threadIdx.x == 0) out[(size_t)N_TOK * DIM] = red[0] * (1.25f / 8388608.f);
}

extern "C" void kernel_launch(void* const* d_in, const int* in_sizes, int n_in,
                              void* d_out, int out_size, void* d_ws, size_t ws_size,
                              hipStream_t stream) {
    const float* x = (const float*)d_in[0];   // [16384,512]
    const float* w = (const float*)d_in[1];   // [8192,512]
    float* out = (float*)d_out;               // 16384*512 + 1

    char* W = (char*)d_ws;
    u16*   xhi   = (u16*)(W);                        // 16 MiB
    u16*   xlo   = (u16*)(W + 16777216);             // 16 MiB
    u16*   whi   = (u16*)(W + 33554432);             // 8 MiB
    u16*   wlo   = (u16*)(W + 41943040);             // 8 MiB
    float* wsq   = (float*)(W + 50331648);           // 32 KiB
    float* wsval = (float*)(W + 50364416);           // 256 KiB
    int*   wsidx = (int*)  (W + 50626560);           // 256 KiB
    float* lossp = (float*)(W + 50888704);           // 16 KiB

    prep_x_kernel<<<N_TOK * DIM / 1024, 256, 0, stream>>>(x, xhi, xlo);
    prep_w_kernel<<<N_EMB / 4, 256, 0, stream>>>(w, whi, wlo, wsq);
    dim3 g(N_TOK / 128, KSPLIT);
    gemm_argmin_kernel<<<g, 256, 0, stream>>>(xhi, xlo, whi, wlo, wsq, wsval, wsidx);
    gather_loss_kernel<<<N_TOK / 4, 256, 0, stream>>>(w, x, wsval, wsidx, out, lossp);
    loss_final_kernel<<<1, 256, 0, stream>>>(lossp, out);
}